// Round 6
// baseline (1134.891 us; speedup 1.0000x reference)
//
#include <hip/hip_runtime.h>
#include <hip/hip_bf16.h>

typedef __hip_bfloat16 bf16;
typedef __attribute__((ext_vector_type(8))) short short8;
typedef __attribute__((ext_vector_type(4))) float f32x4;

#define S_LEN 512
#define DIM   512
#define BATCH 128
#define ROWS  (BATCH * S_LEN)

__device__ inline unsigned short f2bu(float f){
    bf16 h = __float2bfloat16(f);
    return *reinterpret_cast<unsigned short*>(&h);
}
__device__ inline float ld_in(const void* p, size_t i, int f32){
    return f32 ? ((const float*)p)[i] : __bfloat162float(((const bf16*)p)[i]);
}

// async global->LDS, 16B per lane; LDS dest = wave-uniform base + lane*16
typedef __attribute__((address_space(1))) const unsigned int gu32;
typedef __attribute__((address_space(3))) unsigned int lu32;
__device__ __forceinline__ void gld16(const void* g, void* l){
    __builtin_amdgcn_global_load_lds((gu32*)g, (lu32*)l, 16, 0, 0);
}

// swizzled LDS fragment read: byte = (row*128 + koff*2) ^ ((row&7)<<4)
// (matches the pre-swizzled global source column permutation at stage time)
__device__ __forceinline__ short8 lds_frag(const unsigned short* base, int row, int koff){
    const unsigned off = ((unsigned)(row*128 + koff*2)) ^ (((unsigned)(row & 7)) << 4);
    return *(const short8*)((const char*)base + off);
}

// ---------------------------------------------------------------------------
// dtype detector (unchanged)
// ---------------------------------------------------------------------------
__global__ void detect_dtype(const unsigned int* __restrict__ x, int* __restrict__ flag)
{
    __shared__ int cnt;
    if (threadIdx.x == 0) cnt = 0;
    __syncthreads();
    int loc = 0;
    for (int i = threadIdx.x; i < 8192; i += 256)
        if (((x[i] >> 7) & 0xFFu) == 0xFFu) loc++;
    atomicAdd(&cnt, loc);
    __syncthreads();
    if (threadIdx.x == 0) *flag = (cnt > 0) ? 1 : 0;
}

// ---------------------------------------------------------------------------
// converters (unchanged)
// ---------------------------------------------------------------------------
__global__ void conv_tr(const void* __restrict__ in, bf16* __restrict__ outp,
                        const int* __restrict__ flagp)
{
    const int f32 = *flagp;
    __shared__ unsigned short tile[32][33];
    const int bx = blockIdx.x, by = blockIdx.y;
    const int tx = threadIdx.x, ty = threadIdx.y;   // 32 x 8
    #pragma unroll
    for (int j = 0; j < 32; j += 8)
        tile[ty + j][tx] = f2bu(ld_in(in, (size_t)(by*32 + ty + j)*DIM + bx*32 + tx, f32));
    __syncthreads();
    #pragma unroll
    for (int j = 0; j < 32; j += 8) {
        unsigned short u = tile[tx][ty + j];
        outp[(size_t)(bx*32 + ty + j)*DIM + by*32 + tx] = *reinterpret_cast<bf16*>(&u);
    }
}

__global__ void conv_cp(const void* __restrict__ in, bf16* __restrict__ outp,
                        const int* __restrict__ flagp)
{
    const int f32 = *flagp;
    const size_t i = (size_t)blockIdx.x*256 + threadIdx.x;
    outp[i] = __float2bfloat16(ld_in(in, i, f32));
}

// x (any dtype) -> bf16, 8 elems/thread, chunk at element offset eoff
__global__ void conv_x(const void* __restrict__ X, size_t eoff, bf16* __restrict__ xb,
                       const int* __restrict__ flagp)
{
    const int f32 = *flagp;
    const size_t i = ((size_t)blockIdx.x*256 + threadIdx.x)*8;
    if (f32) {
        const float* p = (const float*)X + eoff + i;
        float4 a = *(const float4*)p;
        float4 b = *(const float4*)(p + 4);
        __align__(16) unsigned short wv[8];
        wv[0]=f2bu(a.x); wv[1]=f2bu(a.y); wv[2]=f2bu(a.z); wv[3]=f2bu(a.w);
        wv[4]=f2bu(b.x); wv[5]=f2bu(b.y); wv[6]=f2bu(b.z); wv[7]=f2bu(b.w);
        *(uint4*)(xb + i) = *(const uint4*)wv;
    } else {
        *(uint4*)(xb + i) = *(const uint4*)((const bf16*)X + eoff + i);
    }
}

// ---------------------------------------------------------------------------
// dvec[n] = sum_k bv[k]*WoT[n][k] + bo[n]; bvec[n] = dvec[n] + bi[n]
// ---------------------------------------------------------------------------
__global__ void cvec_kernel(const bf16* __restrict__ WoT, const void* __restrict__ bv,
                            const void* __restrict__ bo, const void* __restrict__ bi,
                            const int* __restrict__ flagp,
                            float* __restrict__ dvec, float* __restrict__ bvec)
{
    const int f32 = *flagp;
    const int n = blockIdx.x * 4 + (threadIdx.x >> 6);
    const int lane = threadIdx.x & 63;
    float acc = 0.f;
    for (int k = lane; k < DIM; k += 64)
        acc += ld_in(bv, k, f32) * __bfloat162float(WoT[(size_t)n*DIM + k]);
    #pragma unroll
    for (int o = 32; o > 0; o >>= 1) acc += __shfl_down(acc, o, 64);
    if (lane == 0) {
        const float dd = acc + ld_in(bo, n, f32);
        dvec[n] = dd;
        bvec[n] = dd + ld_in(bi, n, f32);
    }
}

// special A rows for the big passes: A1[b]=bf16(U0[b]-d), V0b=bf16(V0), Zr=0
__global__ void prep_aux(const float* __restrict__ U0, const float* __restrict__ V0,
                         const float* __restrict__ dvec,
                         bf16* __restrict__ A1, bf16* __restrict__ V0b, bf16* __restrict__ Zr)
{
    const int idx = blockIdx.x * 256 + threadIdx.x;     // 65536
    const int n = idx & 511;
    A1[idx]  = __float2bfloat16(U0[idx] - dvec[n]);
    V0b[idx] = __float2bfloat16(V0[idx]);
    if (idx < 512) Zr[idx] = __float2bfloat16(0.f);
}

// ---------------------------------------------------------------------------
// Old padded-LDS tile core (kept for the small setup GEMMs)
// ---------------------------------------------------------------------------
#define TILE_PROLOGUE                                                          \
    __shared__ __align__(16) unsigned short As[128][72];                       \
    __shared__ __align__(16) unsigned short Bs[128][72];                       \
    const int tid  = threadIdx.x;                                              \
    const int lane = tid & 63;                                                 \
    const int wave = tid >> 6;                                                 \
    const int wm = (wave & 1) * 64;                                            \
    const int wn = (wave >> 1) * 64;                                           \
    const int cn = lane & 15;                                                  \
    const int quad = lane >> 4;                                                \
    f32x4 acc[4][4];                                                           \
    _Pragma("unroll")                                                          \
    for (int i = 0; i < 4; ++i)                                                \
        _Pragma("unroll")                                                      \
        for (int j = 0; j < 4; ++j) acc[i][j] = (f32x4){0.f,0.f,0.f,0.f};

#define TILE_MFMA                                                              \
        __syncthreads();                                                       \
        _Pragma("unroll")                                                      \
        for (int ks = 0; ks < 64; ks += 32) {                                  \
            short8 af[4], bfr[4];                                              \
            const int koff = ks + quad*8;                                      \
            _Pragma("unroll")                                                  \
            for (int i = 0; i < 4; ++i) af[i]  = *(const short8*)&As[wm + i*16 + cn][koff]; \
            _Pragma("unroll")                                                  \
            for (int j = 0; j < 4; ++j) bfr[j] = *(const short8*)&Bs[wn + j*16 + cn][koff]; \
            _Pragma("unroll")                                                  \
            for (int i = 0; i < 4; ++i)                                        \
                _Pragma("unroll")                                              \
                for (int j = 0; j < 4; ++j)                                    \
                    acc[i][j] = __builtin_amdgcn_mfma_f32_16x16x32_bf16(af[i], bfr[j], acc[i][j], 0, 0, 0); \
        }                                                                      \
        __syncthreads();

#define STAGE_B(Bt, C0)                                                        \
        {                                                                      \
            int r = tid >> 3; const int c = (tid & 7) * 8;                     \
            _Pragma("unroll")                                                  \
            for (int p = 0; p < 4; ++p, r += 32) {                             \
                uint4 v = *(const uint4*)((Bt) + (size_t)((C0) + r)*DIM + k0 + c); \
                *(uint4*)&Bs[r][c] = v;                                        \
            }                                                                  \
        }

#define STAGE_A_IN(SRC, BASE)                                                  \
                if (f32) {                                                     \
                    const float* sp = (const float*)(SRC) + (BASE);            \
                    float4 a = *(const float4*)sp;                             \
                    float4 b = *(const float4*)(sp + 4);                       \
                    __align__(16) unsigned short w[8];                         \
                    w[0]=f2bu(a.x); w[1]=f2bu(a.y); w[2]=f2bu(a.z); w[3]=f2bu(a.w); \
                    w[4]=f2bu(b.x); w[5]=f2bu(b.y); w[6]=f2bu(b.z); w[7]=f2bu(b.w); \
                    *(uint4*)&As[r][c] = *(const uint4*)w;                     \
                } else {                                                       \
                    *(uint4*)&As[r][c] = *(const uint4*)((const bf16*)(SRC) + (BASE)); \
                }

// ---------------------------------------------------------------------------
// gemm_sq / gemm_row0 / gemm_v0 (unchanged small setup GEMMs)
// ---------------------------------------------------------------------------
__global__ __launch_bounds__(256) void gemm_sq(const bf16* __restrict__ A,
        const bf16* __restrict__ Btm, bf16* __restrict__ Pout, bf16* __restrict__ Tout)
{
    TILE_PROLOGUE
    const int R0 = blockIdx.y * 128;
    const int C0 = blockIdx.x * 128;
    for (int k0 = 0; k0 < DIM; k0 += 64) {
        {
            int r = tid >> 3; const int c = (tid & 7) * 8;
            #pragma unroll
            for (int p = 0; p < 4; ++p, r += 32)
                *(uint4*)&As[r][c] = *(const uint4*)(A + (size_t)(R0 + r)*DIM + k0 + c);
        }
        STAGE_B(Btm, C0)
        TILE_MFMA
    }
    #pragma unroll
    for (int i = 0; i < 4; ++i) {
        const int rowb = R0 + wm + i*16 + quad*4;
        #pragma unroll
        for (int j = 0; j < 4; ++j) {
            const int cc = C0 + wn + j*16 + cn;
            #pragma unroll
            for (int rr = 0; rr < 4; ++rr) {
                const float v = acc[i][j][rr];
                Pout[(size_t)(rowb + rr)*DIM + cc] = __float2bfloat16(v);
                Tout[(size_t)cc*DIM + rowb + rr]  = __float2bfloat16(v);
            }
        }
    }
}

__global__ __launch_bounds__(256) void gemm_row0(const void* __restrict__ X,
        const bf16* __restrict__ WiT, const float* __restrict__ bvec,
        const int* __restrict__ flagp, float* __restrict__ U0)
{
    const int f32 = *flagp;
    TILE_PROLOGUE
    const int C0 = blockIdx.x * 128;
    for (int k0 = 0; k0 < DIM; k0 += 64) {
        {
            int r = tid >> 3; const int c = (tid & 7) * 8;
            #pragma unroll
            for (int p = 0; p < 4; ++p, r += 32) {
                const size_t base = (size_t)r*S_LEN*DIM + k0 + c;
                STAGE_A_IN(X, base)
            }
        }
        STAGE_B(WiT, C0)
        TILE_MFMA
    }
    #pragma unroll
    for (int i = 0; i < 4; ++i) {
        const int rowb = wm + i*16 + quad*4;
        #pragma unroll
        for (int j = 0; j < 4; ++j) {
            const int cc = C0 + wn + j*16 + cn;
            const float bb = bvec[cc];
            #pragma unroll
            for (int rr = 0; rr < 4; ++rr)
                U0[(size_t)(rowb + rr)*DIM + cc] = acc[i][j][rr] + bb;
        }
    }
}

__global__ __launch_bounds__(256) void gemm_v0(const float* __restrict__ U0,
        const bf16* __restrict__ T0, const float* __restrict__ dvec, float* __restrict__ V0)
{
    TILE_PROLOGUE
    const int C0 = blockIdx.x * 128;
    for (int k0 = 0; k0 < DIM; k0 += 64) {
        {
            int r = tid >> 3; const int c = (tid & 7) * 8;
            #pragma unroll
            for (int p = 0; p < 4; ++p, r += 32) {
                __align__(16) unsigned short w[8];
                #pragma unroll
                for (int q = 0; q < 8; ++q)
                    w[q] = f2bu(U0[(size_t)r*DIM + k0 + c + q] - dvec[k0 + c + q]);
                *(uint4*)&As[r][c] = *(const uint4*)w;
            }
        }
        STAGE_B(T0, C0)
        TILE_MFMA
    }
    #pragma unroll
    for (int i = 0; i < 4; ++i) {
        const int rowb = wm + i*16 + quad*4;
        #pragma unroll
        for (int j = 0; j < 4; ++j) {
            const int cc = C0 + wn + j*16 + cn;
            #pragma unroll
            for (int rr = 0; rr < 4; ++rr) {
                const size_t off = (size_t)(rowb + rr)*DIM + cc;
                V0[off] = acc[i][j][rr] + U0[off];
            }
        }
    }
}

// ---------------------------------------------------------------------------
// gemm_big v6: max-TLP m97-simple structure. 128x128 tile, 4 waves (64x64
// each), BK=64, SINGLE-buffer LDS 32 KB -> 4-5 blocks/CU (16-20 waves).
// Plain __syncthreads() (compiler-managed vmcnt/lgkmcnt), NO setprio, NO
// inline-asm waits. Cross-block wave overlap (m114) hides the drain.
// K-half-split fragment reads keep live VGPR <= ~128 (launch_bounds 256,4).
// Same verified swizzle involution (pre-swizzled source col + XOR read).
// MODE 2: xf pass — A = Abf[row], residual = Rf[cc] (bvec)
// MODE 1: level 1 — t==0 -> A1[b], t==1 -> V0b[b], else Abf[row-1]; resid Rf[off]
// MODE 0: level s — t>=shift -> Abf[row-shift] else Zr; resid Rf[off]
// Output: fp32 Of + bf16 Ob dual store, or d_out via flag when TO_OUT.
// Bit-identical math to rounds 1-5.
// ---------------------------------------------------------------------------
template<int MODE, bool TO_OUT>
__global__ __launch_bounds__(256, 4) void gemm_big(
        const bf16* __restrict__ Abf, const bf16* __restrict__ A1,
        const bf16* __restrict__ V0b, const bf16* __restrict__ Zr,
        const bf16* __restrict__ Bt,  const float* __restrict__ Rf,
        float* __restrict__ Of, bf16* __restrict__ Ob,
        void* __restrict__ Oout, size_t eoff, const int* __restrict__ flagp,
        const int shift)
{
    __shared__ __align__(16) unsigned short As[128*64];   // 16 KB
    __shared__ __align__(16) unsigned short Bs[128*64];   // 16 KB
    const int tid  = threadIdx.x;
    const int lane = tid & 63;
    const int w    = tid >> 6;                  // 0..3
    // XCD-grouped decode: 4 col-blocks sharing an A-panel stay adjacent
    const int nb = gridDim.x;                   // (CR/128)*4, %8==0
    const int p0 = blockIdx.x;
    const int L  = (p0 & 7) * (nb >> 3) + (p0 >> 3);
    const int bx = L & 3, by = L >> 2;
    const int R0 = by * 128, C0 = bx * 128;
    const int wm = (w & 1) * 64;
    const int wn = (w >> 1) * 64;
    const int cn = lane & 15;
    const int quad = lane >> 4;
    f32x4 acc[4][4];
    #pragma unroll
    for (int i = 0; i < 4; ++i)
        #pragma unroll
        for (int j = 0; j < 4; ++j) acc[i][j] = (f32x4){0.f,0.f,0.f,0.f};

    // staging: lines of 32 rows x 64 k (4 KB). A: 4 lines, B: 4 lines.
    const int lr  = w*8 + (lane >> 3);                    // 0..31 row-in-line
    const int lcb = ((lane & 7) ^ (lane >> 3)) * 8;       // pre-swizzled col
    const int ldst = w * 512;                             // ushort offset in line
    const bf16* aln[4];
    const bf16* bln[4];
    #pragma unroll
    for (int l = 0; l < 4; ++l) {
        const int grow = R0 + l*32 + lr;
        const bf16* a;
        if (MODE == 2) {
            a = Abf + (size_t)grow*DIM;
        } else if (MODE == 1) {
            const int t = grow & (S_LEN - 1);
            if      (t == 0) a = A1  + (size_t)(grow >> 9)*DIM;
            else if (t == 1) a = V0b + (size_t)(grow >> 9)*DIM;
            else             a = Abf + (size_t)(grow - 1)*DIM;
        } else {
            const int t = grow & (S_LEN - 1);
            a = (t >= shift) ? (Abf + (size_t)(grow - shift)*DIM) : Zr;
        }
        aln[l] = a + lcb;
        bln[l] = Bt + (size_t)(C0 + l*32 + lr)*DIM + lcb;
    }

    for (int kt = 0; kt < 8; ++kt) {
        const int kn = kt * 64;
        // stage tile kt (single buffer)
        #pragma unroll
        for (int l = 0; l < 4; ++l) {
            gld16(aln[l] + kn, &As[l*2048 + ldst]);
            gld16(bln[l] + kn, &Bs[l*2048 + ldst]);
        }
        __syncthreads();    // drains vmcnt -> LDS visible to all waves
        #pragma unroll
        for (int ks = 0; ks < 64; ks += 32) {
            short8 af[4], bfr[4];
            const int koff = ks + quad*8;
            #pragma unroll
            for (int i = 0; i < 4; ++i) af[i]  = lds_frag(As, wm + i*16 + cn, koff);
            #pragma unroll
            for (int j = 0; j < 4; ++j) bfr[j] = lds_frag(Bs, wn + j*16 + cn, koff);
            #pragma unroll
            for (int i = 0; i < 4; ++i)
                #pragma unroll
                for (int j = 0; j < 4; ++j)
                    acc[i][j] = __builtin_amdgcn_mfma_f32_16x16x32_bf16(af[i], bfr[j], acc[i][j], 0, 0, 0);
        }
        __syncthreads();    // all reads done before next stage overwrites
    }

    const int f32o = TO_OUT ? *flagp : 0;
    #pragma unroll
    for (int i = 0; i < 4; ++i) {
        const int rowb = R0 + wm + i*16 + quad*4;
        #pragma unroll
        for (int j = 0; j < 4; ++j) {
            const int cc = C0 + wn + j*16 + cn;
            #pragma unroll
            for (int rr = 0; rr < 4; ++rr) {
                const size_t off = (size_t)(rowb + rr)*DIM + cc;
                const float res = (MODE == 2) ? Rf[cc] : Rf[off];
                const float v = acc[i][j][rr] + res;
                if (TO_OUT) {
                    if (f32o) ((float*)Oout)[eoff + off] = v;
                    else      ((bf16*)Oout)[eoff + off]  = __float2bfloat16(v);
                } else {
                    Of[off] = v;
                    Ob[off] = __float2bfloat16(v);
                }
            }
        }
    }
}

// final_state[b,:] = outputs[b, len_b - 1, :]
__global__ void gather_final(void* __restrict__ out, const int* __restrict__ lens,
                             const int* __restrict__ flagp)
{
    const int f32 = *flagp;
    const int idx = blockIdx.x * 256 + threadIdx.x;
    const int b = idx >> 9, n = idx & 511;
    int L = lens[b];
    if (L < 1) L = 1;
    if (L > S_LEN) L = S_LEN;
    const size_t src = ((size_t)b*S_LEN + (L - 1))*DIM + n;
    const size_t dst = (size_t)ROWS*DIM + idx;
    if (f32) ((float*)out)[dst] = ((const float*)out)[src];
    else     ((bf16*)out)[dst]  = ((const bf16*)out)[src];
}

// ---------------------------------------------------------------------------
extern "C" void kernel_launch(void* const* d_in, const int* in_sizes, int n_in,
                              void* d_out, int out_size, void* d_ws, size_t ws_size,
                              hipStream_t stream)
{
    const void* X  = d_in[0];
    const void* Wi = d_in[1];
    const void* bi = d_in[2];
    // d_in[3..6] = Wq, bq, Wk, bk — dead (softmax over singleton axis == 1)
    const void* Wv = d_in[7];
    const void* bv = d_in[8];
    const void* Wo = d_in[9];
    const void* bo = d_in[10];
    const int* lens = (const int*)d_in[11];
    char* ws = (char*)d_ws;

    // ---- fixed workspace layout ----
    const size_t MATB = (size_t)DIM * DIM * sizeof(bf16);    // 524288
    bf16* WiT = (bf16*)(ws + 0*MATB);
    bf16* WoT = (bf16*)(ws + 1*MATB);
    bf16* Wvb = (bf16*)(ws + 2*MATB);
    bf16* S2  = (bf16*)(ws + 3*MATB);   // W, then W^4
    bf16* S3  = (bf16*)(ws + 4*MATB);   // W^2, then W^8
    bf16* T0  = (bf16*)(ws + 5*MATB);   // W^T
    bf16* T1  = (bf16*)(ws + 6*MATB);   // (W^2)^T
    bf16* T2  = (bf16*)(ws + 7*MATB);   // (W^4)^T
    bf16* T3  = (bf16*)(ws + 8*MATB);   // (W^8)^T
    size_t off = 9*MATB;
    float* dvec = (float*)(ws + off); off += 2048;
    float* bvec = (float*)(ws + off); off += 2048;
    int*   flag = (int*)  (ws + off); off += 256;
    float* U0   = (float*)(ws + off); off += (size_t)BATCH*DIM*4;  // 262144
    float* V0   = (float*)(ws + off); off += (size_t)BATCH*DIM*4;
    bf16*  A1   = (bf16*) (ws + off); off += (size_t)BATCH*DIM*2;  // 131072
    bf16*  V0b  = (bf16*) (ws + off); off += (size_t)BATCH*DIM*2;
    bf16*  Zr   = (bf16*) (ws + off); off += 1024;
    off = (off + 1023) & ~(size_t)1023;
    char* dyn = ws + off;
    const size_t avail = ws_size > off ? ws_size - off : 0;

    // per-chunk: xbf (CR*1024) + Uf (CR*2048) + Ub (CR*1024) + Vf (CR*2048) + Vb (CR*1024)
    int CR = 512;
    for (long cr = 65536; cr >= 512; cr >>= 1)
        if ((size_t)cr * 7168 <= avail) { CR = (int)cr; break; }

    bf16*  xbf = (bf16*) dyn;
    float* Uf  = (float*)(dyn + (size_t)CR*1024);
    bf16*  Ub  = (bf16*) (dyn + (size_t)CR*3072);
    float* Vf  = (float*)(dyn + (size_t)CR*4096);
    bf16*  Vb  = (bf16*) (dyn + (size_t)CR*6144);

    detect_dtype<<<1, 256, 0, stream>>>((const unsigned int*)X, flag);
    conv_tr<<<dim3(16,16), dim3(32,8), 0, stream>>>(Wi, WiT, flag);
    conv_tr<<<dim3(16,16), dim3(32,8), 0, stream>>>(Wo, WoT, flag);
    conv_cp<<<1024, 256, 0, stream>>>(Wv, Wvb, flag);
    cvec_kernel<<<128, 256, 0, stream>>>(WoT, bv, bo, bi, flag, dvec, bvec);
    gemm_sq<<<dim3(4,4), 256, 0, stream>>>(Wvb, WoT, S2, T0);   // W
    gemm_sq<<<dim3(4,4), 256, 0, stream>>>(S2, T0, S3, T1);     // W^2
    gemm_sq<<<dim3(4,4), 256, 0, stream>>>(S3, T1, S2, T2);     // W^4
    gemm_sq<<<dim3(4,4), 256, 0, stream>>>(S2, T2, S3, T3);     // W^8
    gemm_row0<<<dim3(4,1), 256, 0, stream>>>(X, WiT, bvec, flag, U0);
    gemm_v0<<<dim3(4,1), 256, 0, stream>>>(U0, T0, dvec, V0);
    prep_aux<<<256, 256, 0, stream>>>(U0, V0, dvec, A1, V0b, Zr);

    const int NC = ROWS / CR;
    const int nb = (CR / 128) * 4;   // 128-row tiles x 4 col-blocks
    for (int c = 0; c < NC; ++c) {
        const size_t eoff = (size_t)c*CR*DIM;
        const size_t boff = (size_t)(c*(CR/S_LEN))*DIM;
        conv_x<<<CR/4, 256, 0, stream>>>(X, eoff, xbf, flag);
        gemm_big<2,false><<<nb, 256, 0, stream>>>(xbf, nullptr, nullptr, Zr,
                WiT, bvec, Uf, Ub, nullptr, 0, flag, 0);
        gemm_big<1,false><<<nb, 256, 0, stream>>>(Ub, A1 + boff, V0b + boff, Zr,
                T0, Uf, Vf, Vb, nullptr, 0, flag, 1);
        gemm_big<0,false><<<nb, 256, 0, stream>>>(Vb, nullptr, nullptr, Zr,
                T1, Vf, Uf, Ub, nullptr, 0, flag, 2);
        gemm_big<0,false><<<nb, 256, 0, stream>>>(Ub, nullptr, nullptr, Zr,
                T2, Uf, Vf, Vb, nullptr, 0, flag, 4);
        gemm_big<0,true ><<<nb, 256, 0, stream>>>(Vb, nullptr, nullptr, Zr,
                T3, Vf, nullptr, nullptr, d_out, eoff, flag, 8);
    }
    gather_final<<<256, 256, 0, stream>>>(d_out, lens, flag);
}

// Round 7
// 1022.912 us; speedup vs baseline: 1.1095x; 1.1095x over previous
//
#include <hip/hip_runtime.h>
#include <hip/hip_bf16.h>

typedef __hip_bfloat16 bf16;
typedef __attribute__((ext_vector_type(8))) short short8;
typedef __attribute__((ext_vector_type(4))) float f32x4;

#define S_LEN 512
#define DIM   512
#define BATCH 128
#define ROWS  (BATCH * S_LEN)

__device__ inline unsigned short f2bu(float f){
    bf16 h = __float2bfloat16(f);
    return *reinterpret_cast<unsigned short*>(&h);
}
__device__ inline float ld_in(const void* p, size_t i, int f32){
    return f32 ? ((const float*)p)[i] : __bfloat162float(((const bf16*)p)[i]);
}

// async global->LDS, 16B per lane; LDS dest = wave-uniform base + lane*16
typedef __attribute__((address_space(1))) const unsigned int gu32;
typedef __attribute__((address_space(3))) unsigned int lu32;
__device__ __forceinline__ void gld16(const void* g, void* l){
    __builtin_amdgcn_global_load_lds((gu32*)g, (lu32*)l, 16, 0, 0);
}

// swizzled LDS fragment read: byte = (row*128 + koff*2) ^ ((row&7)<<4)
// (matches the pre-swizzled global source column permutation at stage time)
__device__ __forceinline__ short8 lds_frag(const unsigned short* base, int row, int koff){
    const unsigned off = ((unsigned)(row*128 + koff*2)) ^ (((unsigned)(row & 7)) << 4);
    return *(const short8*)((const char*)base + off);
}

// ---------------------------------------------------------------------------
// dtype detector (unchanged)
// ---------------------------------------------------------------------------
__global__ void detect_dtype(const unsigned int* __restrict__ x, int* __restrict__ flag)
{
    __shared__ int cnt;
    if (threadIdx.x == 0) cnt = 0;
    __syncthreads();
    int loc = 0;
    for (int i = threadIdx.x; i < 8192; i += 256)
        if (((x[i] >> 7) & 0xFFu) == 0xFFu) loc++;
    atomicAdd(&cnt, loc);
    __syncthreads();
    if (threadIdx.x == 0) *flag = (cnt > 0) ? 1 : 0;
}

// ---------------------------------------------------------------------------
// converters (unchanged)
// ---------------------------------------------------------------------------
__global__ void conv_tr(const void* __restrict__ in, bf16* __restrict__ outp,
                        const int* __restrict__ flagp)
{
    const int f32 = *flagp;
    __shared__ unsigned short tile[32][33];
    const int bx = blockIdx.x, by = blockIdx.y;
    const int tx = threadIdx.x, ty = threadIdx.y;   // 32 x 8
    #pragma unroll
    for (int j = 0; j < 32; j += 8)
        tile[ty + j][tx] = f2bu(ld_in(in, (size_t)(by*32 + ty + j)*DIM + bx*32 + tx, f32));
    __syncthreads();
    #pragma unroll
    for (int j = 0; j < 32; j += 8) {
        unsigned short u = tile[tx][ty + j];
        outp[(size_t)(bx*32 + ty + j)*DIM + by*32 + tx] = *reinterpret_cast<bf16*>(&u);
    }
}

__global__ void conv_cp(const void* __restrict__ in, bf16* __restrict__ outp,
                        const int* __restrict__ flagp)
{
    const int f32 = *flagp;
    const size_t i = (size_t)blockIdx.x*256 + threadIdx.x;
    outp[i] = __float2bfloat16(ld_in(in, i, f32));
}

// x (any dtype) -> bf16, 8 elems/thread, chunk at element offset eoff
__global__ void conv_x(const void* __restrict__ X, size_t eoff, bf16* __restrict__ xb,
                       const int* __restrict__ flagp)
{
    const int f32 = *flagp;
    const size_t i = ((size_t)blockIdx.x*256 + threadIdx.x)*8;
    if (f32) {
        const float* p = (const float*)X + eoff + i;
        float4 a = *(const float4*)p;
        float4 b = *(const float4*)(p + 4);
        __align__(16) unsigned short wv[8];
        wv[0]=f2bu(a.x); wv[1]=f2bu(a.y); wv[2]=f2bu(a.z); wv[3]=f2bu(a.w);
        wv[4]=f2bu(b.x); wv[5]=f2bu(b.y); wv[6]=f2bu(b.z); wv[7]=f2bu(b.w);
        *(uint4*)(xb + i) = *(const uint4*)wv;
    } else {
        *(uint4*)(xb + i) = *(const uint4*)((const bf16*)X + eoff + i);
    }
}

// ---------------------------------------------------------------------------
// dvec[n] = sum_k bv[k]*WoT[n][k] + bo[n]; bvec[n] = dvec[n] + bi[n]
// ---------------------------------------------------------------------------
__global__ void cvec_kernel(const bf16* __restrict__ WoT, const void* __restrict__ bv,
                            const void* __restrict__ bo, const void* __restrict__ bi,
                            const int* __restrict__ flagp,
                            float* __restrict__ dvec, float* __restrict__ bvec)
{
    const int f32 = *flagp;
    const int n = blockIdx.x * 4 + (threadIdx.x >> 6);
    const int lane = threadIdx.x & 63;
    float acc = 0.f;
    for (int k = lane; k < DIM; k += 64)
        acc += ld_in(bv, k, f32) * __bfloat162float(WoT[(size_t)n*DIM + k]);
    #pragma unroll
    for (int o = 32; o > 0; o >>= 1) acc += __shfl_down(acc, o, 64);
    if (lane == 0) {
        const float dd = acc + ld_in(bo, n, f32);
        dvec[n] = dd;
        bvec[n] = dd + ld_in(bi, n, f32);
    }
}

// special A rows for the big passes: A1[b]=bf16(U0[b]-d), V0b=bf16(V0), Zr=0
__global__ void prep_aux(const float* __restrict__ U0, const float* __restrict__ V0,
                         const float* __restrict__ dvec,
                         bf16* __restrict__ A1, bf16* __restrict__ V0b, bf16* __restrict__ Zr)
{
    const int idx = blockIdx.x * 256 + threadIdx.x;     // 65536
    const int n = idx & 511;
    A1[idx]  = __float2bfloat16(U0[idx] - dvec[n]);
    V0b[idx] = __float2bfloat16(V0[idx]);
    if (idx < 512) Zr[idx] = __float2bfloat16(0.f);
}

// ---------------------------------------------------------------------------
// Old padded-LDS tile core (kept for the small setup GEMMs)
// ---------------------------------------------------------------------------
#define TILE_PROLOGUE                                                          \
    __shared__ __align__(16) unsigned short As[128][72];                       \
    __shared__ __align__(16) unsigned short Bs[128][72];                       \
    const int tid  = threadIdx.x;                                              \
    const int lane = tid & 63;                                                 \
    const int wave = tid >> 6;                                                 \
    const int wm = (wave & 1) * 64;                                            \
    const int wn = (wave >> 1) * 64;                                           \
    const int cn = lane & 15;                                                  \
    const int quad = lane >> 4;                                                \
    f32x4 acc[4][4];                                                           \
    _Pragma("unroll")                                                          \
    for (int i = 0; i < 4; ++i)                                                \
        _Pragma("unroll")                                                      \
        for (int j = 0; j < 4; ++j) acc[i][j] = (f32x4){0.f,0.f,0.f,0.f};

#define TILE_MFMA                                                              \
        __syncthreads();                                                       \
        _Pragma("unroll")                                                      \
        for (int ks = 0; ks < 64; ks += 32) {                                  \
            short8 af[4], bfr[4];                                              \
            const int koff = ks + quad*8;                                      \
            _Pragma("unroll")                                                  \
            for (int i = 0; i < 4; ++i) af[i]  = *(const short8*)&As[wm + i*16 + cn][koff]; \
            _Pragma("unroll")                                                  \
            for (int j = 0; j < 4; ++j) bfr[j] = *(const short8*)&Bs[wn + j*16 + cn][koff]; \
            _Pragma("unroll")                                                  \
            for (int i = 0; i < 4; ++i)                                        \
                _Pragma("unroll")                                              \
                for (int j = 0; j < 4; ++j)                                    \
                    acc[i][j] = __builtin_amdgcn_mfma_f32_16x16x32_bf16(af[i], bfr[j], acc[i][j], 0, 0, 0); \
        }                                                                      \
        __syncthreads();

#define STAGE_B(Bt, C0)                                                        \
        {                                                                      \
            int r = tid >> 3; const int c = (tid & 7) * 8;                     \
            _Pragma("unroll")                                                  \
            for (int p = 0; p < 4; ++p, r += 32) {                             \
                uint4 v = *(const uint4*)((Bt) + (size_t)((C0) + r)*DIM + k0 + c); \
                *(uint4*)&Bs[r][c] = v;                                        \
            }                                                                  \
        }

#define STAGE_A_IN(SRC, BASE)                                                  \
                if (f32) {                                                     \
                    const float* sp = (const float*)(SRC) + (BASE);            \
                    float4 a = *(const float4*)sp;                             \
                    float4 b = *(const float4*)(sp + 4);                       \
                    __align__(16) unsigned short w[8];                         \
                    w[0]=f2bu(a.x); w[1]=f2bu(a.y); w[2]=f2bu(a.z); w[3]=f2bu(a.w); \
                    w[4]=f2bu(b.x); w[5]=f2bu(b.y); w[6]=f2bu(b.z); w[7]=f2bu(b.w); \
                    *(uint4*)&As[r][c] = *(const uint4*)w;                     \
                } else {                                                       \
                    *(uint4*)&As[r][c] = *(const uint4*)((const bf16*)(SRC) + (BASE)); \
                }

// ---------------------------------------------------------------------------
// gemm_sq / gemm_row0 / gemm_v0 (unchanged small setup GEMMs)
// ---------------------------------------------------------------------------
__global__ __launch_bounds__(256) void gemm_sq(const bf16* __restrict__ A,
        const bf16* __restrict__ Btm, bf16* __restrict__ Pout, bf16* __restrict__ Tout)
{
    TILE_PROLOGUE
    const int R0 = blockIdx.y * 128;
    const int C0 = blockIdx.x * 128;
    for (int k0 = 0; k0 < DIM; k0 += 64) {
        {
            int r = tid >> 3; const int c = (tid & 7) * 8;
            #pragma unroll
            for (int p = 0; p < 4; ++p, r += 32)
                *(uint4*)&As[r][c] = *(const uint4*)(A + (size_t)(R0 + r)*DIM + k0 + c);
        }
        STAGE_B(Btm, C0)
        TILE_MFMA
    }
    #pragma unroll
    for (int i = 0; i < 4; ++i) {
        const int rowb = R0 + wm + i*16 + quad*4;
        #pragma unroll
        for (int j = 0; j < 4; ++j) {
            const int cc = C0 + wn + j*16 + cn;
            #pragma unroll
            for (int rr = 0; rr < 4; ++rr) {
                const float v = acc[i][j][rr];
                Pout[(size_t)(rowb + rr)*DIM + cc] = __float2bfloat16(v);
                Tout[(size_t)cc*DIM + rowb + rr]  = __float2bfloat16(v);
            }
        }
    }
}

__global__ __launch_bounds__(256) void gemm_row0(const void* __restrict__ X,
        const bf16* __restrict__ WiT, const float* __restrict__ bvec,
        const int* __restrict__ flagp, float* __restrict__ U0)
{
    const int f32 = *flagp;
    TILE_PROLOGUE
    const int C0 = blockIdx.x * 128;
    for (int k0 = 0; k0 < DIM; k0 += 64) {
        {
            int r = tid >> 3; const int c = (tid & 7) * 8;
            #pragma unroll
            for (int p = 0; p < 4; ++p, r += 32) {
                const size_t base = (size_t)r*S_LEN*DIM + k0 + c;
                STAGE_A_IN(X, base)
            }
        }
        STAGE_B(WiT, C0)
        TILE_MFMA
    }
    #pragma unroll
    for (int i = 0; i < 4; ++i) {
        const int rowb = wm + i*16 + quad*4;
        #pragma unroll
        for (int j = 0; j < 4; ++j) {
            const int cc = C0 + wn + j*16 + cn;
            const float bb = bvec[cc];
            #pragma unroll
            for (int rr = 0; rr < 4; ++rr)
                U0[(size_t)(rowb + rr)*DIM + cc] = acc[i][j][rr] + bb;
        }
    }
}

__global__ __launch_bounds__(256) void gemm_v0(const float* __restrict__ U0,
        const bf16* __restrict__ T0, const float* __restrict__ dvec, float* __restrict__ V0)
{
    TILE_PROLOGUE
    const int C0 = blockIdx.x * 128;
    for (int k0 = 0; k0 < DIM; k0 += 64) {
        {
            int r = tid >> 3; const int c = (tid & 7) * 8;
            #pragma unroll
            for (int p = 0; p < 4; ++p, r += 32) {
                __align__(16) unsigned short w[8];
                #pragma unroll
                for (int q = 0; q < 8; ++q)
                    w[q] = f2bu(U0[(size_t)r*DIM + k0 + c + q] - dvec[k0 + c + q]);
                *(uint4*)&As[r][c] = *(const uint4*)w;
            }
        }
        STAGE_B(T0, C0)
        TILE_MFMA
    }
    #pragma unroll
    for (int i = 0; i < 4; ++i) {
        const int rowb = wm + i*16 + quad*4;
        #pragma unroll
        for (int j = 0; j < 4; ++j) {
            const int cc = C0 + wn + j*16 + cn;
            #pragma unroll
            for (int rr = 0; rr < 4; ++rr) {
                const size_t off = (size_t)(rowb + rr)*DIM + cc;
                V0[off] = acc[i][j][rr] + U0[off];
            }
        }
    }
}

// ---------------------------------------------------------------------------
// gemm_big v7: deep-stream schedule. 64x128 tile (r5 geometry, 4 waves,
// 2Mx2N 32x64/wave), BK=64, 3-DEEP LDS ring (72 KB -> 2 blocks/CU).
// Prologue stages tiles 0,1,2. Per step u: vmcnt(12) [tile u complete,
// tiles u+1,u+2 still in flight] -> barrier -> compute u -> barrier ->
// stage tile u+3 into the freed slot. vmcnt NEVER drains to 0 in the loop:
// 12-18 gld16/thread (~96-144 KB/CU) continuously in flight.
// Math/swizzle/MODE/epilogue identical to r5 (bit-identical output).
// ---------------------------------------------------------------------------
template<int MODE, bool TO_OUT>
__global__ __launch_bounds__(256, 2) void gemm_big(
        const bf16* __restrict__ Abf, const bf16* __restrict__ A1,
        const bf16* __restrict__ V0b, const bf16* __restrict__ Zr,
        const bf16* __restrict__ Bt,  const float* __restrict__ Rf,
        float* __restrict__ Of, bf16* __restrict__ Ob,
        void* __restrict__ Oout, size_t eoff, const int* __restrict__ flagp,
        const int shift)
{
    __shared__ __align__(16) unsigned short As[3][64*64];    // 3 x 8 KB
    __shared__ __align__(16) unsigned short Bs[3][128*64];   // 3 x 16 KB
    const int tid  = threadIdx.x;
    const int lane = tid & 63;
    const int w    = tid >> 6;                  // 0..3
    // XCD-grouped decode: 4 col-blocks sharing an A-panel stay adjacent
    const int nb = gridDim.x;                   // (CR/64)*4, %8==0
    const int p0 = blockIdx.x;
    const int L  = (p0 & 7) * (nb >> 3) + (p0 >> 3);
    const int bx = L & 3, by = L >> 2;
    const int R0 = by * 64, C0 = bx * 128;
    const int wm = (w & 1) * 32;                // 2 row-groups of 32
    const int wn = (w >> 1) * 64;               // 2 col-groups of 64
    const int cn = lane & 15;
    const int quad = lane >> 4;
    f32x4 acc[2][4];
    #pragma unroll
    for (int i = 0; i < 2; ++i)
        #pragma unroll
        for (int j = 0; j < 4; ++j) acc[i][j] = (f32x4){0.f,0.f,0.f,0.f};

    // staging: lines of 32 rows x 64 k (4 KB). A: 2 lines, B: 4 lines.
    const int lr  = w*8 + (lane >> 3);                    // 0..31 row-in-line
    const int lcb = ((lane & 7) ^ (lane >> 3)) * 8;       // pre-swizzled col
    const int ldst = w * 512;                             // ushort offset in line
    const bf16* aln[2];
    const bf16* bln[4];
    #pragma unroll
    for (int l = 0; l < 2; ++l) {
        const int grow = R0 + l*32 + lr;
        const bf16* a;
        if (MODE == 2) {
            a = Abf + (size_t)grow*DIM;
        } else if (MODE == 1) {
            const int t = grow & (S_LEN - 1);
            if      (t == 0) a = A1  + (size_t)(grow >> 9)*DIM;
            else if (t == 1) a = V0b + (size_t)(grow >> 9)*DIM;
            else             a = Abf + (size_t)(grow - 1)*DIM;
        } else {
            const int t = grow & (S_LEN - 1);
            a = (t >= shift) ? (Abf + (size_t)(grow - shift)*DIM) : Zr;
        }
        aln[l] = a + lcb;
    }
    #pragma unroll
    for (int l = 0; l < 4; ++l)
        bln[l] = Bt + (size_t)(C0 + l*32 + lr)*DIM + lcb;

#define STAGE(SLOT, KN)                                                        \
    {                                                                          \
        gld16(aln[0] + (KN), &As[SLOT][0*2048 + ldst]);                        \
        gld16(aln[1] + (KN), &As[SLOT][1*2048 + ldst]);                        \
        gld16(bln[0] + (KN), &Bs[SLOT][0*2048 + ldst]);                        \
        gld16(bln[1] + (KN), &Bs[SLOT][1*2048 + ldst]);                        \
        gld16(bln[2] + (KN), &Bs[SLOT][2*2048 + ldst]);                        \
        gld16(bln[3] + (KN), &Bs[SLOT][3*2048 + ldst]);                        \
    }

    // prologue: stage tiles 0,1,2 into slots 0,1,2 (18 loads in flight)
    STAGE(0, 0)
    STAGE(1, 64)
    STAGE(2, 128)

#define STEP(U, VM)                                                            \
    {                                                                          \
        asm volatile("s_waitcnt vmcnt(" #VM ")" ::: "memory");                 \
        __builtin_amdgcn_s_barrier();                                          \
        const unsigned short* Ac = &As[(U) % 3][0];                            \
        const unsigned short* Bc = &Bs[(U) % 3][0];                            \
        short8 af[2][2], bfr[4][2];                                            \
        _Pragma("unroll")                                                      \
        for (int i = 0; i < 2; ++i) {                                          \
            af[i][0] = lds_frag(Ac, wm + i*16 + cn,      quad*8);              \
            af[i][1] = lds_frag(Ac, wm + i*16 + cn, 32 + quad*8);              \
        }                                                                      \
        _Pragma("unroll")                                                      \
        for (int j = 0; j < 4; ++j) {                                          \
            bfr[j][0] = lds_frag(Bc, wn + j*16 + cn,      quad*8);             \
            bfr[j][1] = lds_frag(Bc, wn + j*16 + cn, 32 + quad*8);             \
        }                                                                      \
        _Pragma("unroll")                                                      \
        for (int i = 0; i < 2; ++i)                                            \
            _Pragma("unroll")                                                  \
            for (int j = 0; j < 4; ++j) {                                      \
                acc[i][j] = __builtin_amdgcn_mfma_f32_16x16x32_bf16(af[i][0], bfr[j][0], acc[i][j], 0, 0, 0); \
                acc[i][j] = __builtin_amdgcn_mfma_f32_16x16x32_bf16(af[i][1], bfr[j][1], acc[i][j], 0, 0, 0); \
            }                                                                  \
        __builtin_amdgcn_s_barrier();                                          \
        if ((U) + 3 < 8) STAGE((U) % 3, ((U) + 3) * 64)                        \
    }

    STEP(0, 12)
    STEP(1, 12)
    STEP(2, 12)
    STEP(3, 12)
    STEP(4, 12)
    STEP(5, 12)
    STEP(6, 6)
    STEP(7, 0)
#undef STEP
#undef STAGE

    const int f32o = TO_OUT ? *flagp : 0;
    #pragma unroll
    for (int i = 0; i < 2; ++i) {
        const int rowb = R0 + wm + i*16 + quad*4;
        #pragma unroll
        for (int j = 0; j < 4; ++j) {
            const int cc = C0 + wn + j*16 + cn;
            #pragma unroll
            for (int rr = 0; rr < 4; ++rr) {
                const size_t off = (size_t)(rowb + rr)*DIM + cc;
                const float res = (MODE == 2) ? Rf[cc] : Rf[off];
                const float v = acc[i][j][rr] + res;
                if (TO_OUT) {
                    if (f32o) ((float*)Oout)[eoff + off] = v;
                    else      ((bf16*)Oout)[eoff + off]  = __float2bfloat16(v);
                } else {
                    Of[off] = v;
                    Ob[off] = __float2bfloat16(v);
                }
            }
        }
    }
}

// final_state[b,:] = outputs[b, len_b - 1, :]
__global__ void gather_final(void* __restrict__ out, const int* __restrict__ lens,
                             const int* __restrict__ flagp)
{
    const int f32 = *flagp;
    const int idx = blockIdx.x * 256 + threadIdx.x;
    const int b = idx >> 9, n = idx & 511;
    int L = lens[b];
    if (L < 1) L = 1;
    if (L > S_LEN) L = S_LEN;
    const size_t src = ((size_t)b*S_LEN + (L - 1))*DIM + n;
    const size_t dst = (size_t)ROWS*DIM + idx;
    if (f32) ((float*)out)[dst] = ((const float*)out)[src];
    else     ((bf16*)out)[dst]  = ((const bf16*)out)[src];
}

// ---------------------------------------------------------------------------
extern "C" void kernel_launch(void* const* d_in, const int* in_sizes, int n_in,
                              void* d_out, int out_size, void* d_ws, size_t ws_size,
                              hipStream_t stream)
{
    const void* X  = d_in[0];
    const void* Wi = d_in[1];
    const void* bi = d_in[2];
    // d_in[3..6] = Wq, bq, Wk, bk — dead (softmax over singleton axis == 1)
    const void* Wv = d_in[7];
    const void* bv = d_in[8];
    const void* Wo = d_in[9];
    const void* bo = d_in[10];
    const int* lens = (const int*)d_in[11];
    char* ws = (char*)d_ws;

    // ---- fixed workspace layout ----
    const size_t MATB = (size_t)DIM * DIM * sizeof(bf16);    // 524288
    bf16* WiT = (bf16*)(ws + 0*MATB);
    bf16* WoT = (bf16*)(ws + 1*MATB);
    bf16* Wvb = (bf16*)(ws + 2*MATB);
    bf16* S2  = (bf16*)(ws + 3*MATB);   // W, then W^4
    bf16* S3  = (bf16*)(ws + 4*MATB);   // W^2, then W^8
    bf16* T0  = (bf16*)(ws + 5*MATB);   // W^T
    bf16* T1  = (bf16*)(ws + 6*MATB);   // (W^2)^T
    bf16* T2  = (bf16*)(ws + 7*MATB);   // (W^4)^T
    bf16* T3  = (bf16*)(ws + 8*MATB);   // (W^8)^T
    size_t off = 9*MATB;
    float* dvec = (float*)(ws + off); off += 2048;
    float* bvec = (float*)(ws + off); off += 2048;
    int*   flag = (int*)  (ws + off); off += 256;
    float* U0   = (float*)(ws + off); off += (size_t)BATCH*DIM*4;  // 262144
    float* V0   = (float*)(ws + off); off += (size_t)BATCH*DIM*4;
    bf16*  A1   = (bf16*) (ws + off); off += (size_t)BATCH*DIM*2;  // 131072
    bf16*  V0b  = (bf16*) (ws + off); off += (size_t)BATCH*DIM*2;
    bf16*  Zr   = (bf16*) (ws + off); off += 1024;
    off = (off + 1023) & ~(size_t)1023;
    char* dyn = ws + off;
    const size_t avail = ws_size > off ? ws_size - off : 0;

    // per-chunk: xbf (CR*1024) + Uf (CR*2048) + Ub (CR*1024) + Vf (CR*2048) + Vb (CR*1024)
    int CR = 512;
    for (long cr = 65536; cr >= 512; cr >>= 1)
        if ((size_t)cr * 7168 <= avail) { CR = (int)cr; break; }

    bf16*  xbf = (bf16*) dyn;
    float* Uf  = (float*)(dyn + (size_t)CR*1024);
    bf16*  Ub  = (bf16*) (dyn + (size_t)CR*3072);
    float* Vf  = (float*)(dyn + (size_t)CR*4096);
    bf16*  Vb  = (bf16*) (dyn + (size_t)CR*6144);

    detect_dtype<<<1, 256, 0, stream>>>((const unsigned int*)X, flag);
    conv_tr<<<dim3(16,16), dim3(32,8), 0, stream>>>(Wi, WiT, flag);
    conv_tr<<<dim3(16,16), dim3(32,8), 0, stream>>>(Wo, WoT, flag);
    conv_cp<<<1024, 256, 0, stream>>>(Wv, Wvb, flag);
    cvec_kernel<<<128, 256, 0, stream>>>(WoT, bv, bo, bi, flag, dvec, bvec);
    gemm_sq<<<dim3(4,4), 256, 0, stream>>>(Wvb, WoT, S2, T0);   // W
    gemm_sq<<<dim3(4,4), 256, 0, stream>>>(S2, T0, S3, T1);     // W^2
    gemm_sq<<<dim3(4,4), 256, 0, stream>>>(S3, T1, S2, T2);     // W^4
    gemm_sq<<<dim3(4,4), 256, 0, stream>>>(S2, T2, S3, T3);     // W^8
    gemm_row0<<<dim3(4,1), 256, 0, stream>>>(X, WiT, bvec, flag, U0);
    gemm_v0<<<dim3(4,1), 256, 0, stream>>>(U0, T0, dvec, V0);
    prep_aux<<<256, 256, 0, stream>>>(U0, V0, dvec, A1, V0b, Zr);

    const int NC = ROWS / CR;
    const int nb = (CR / 64) * 4;   // 64-row tiles x 4 col-blocks
    for (int c = 0; c < NC; ++c) {
        const size_t eoff = (size_t)c*CR*DIM;
        const size_t boff = (size_t)(c*(CR/S_LEN))*DIM;
        conv_x<<<CR/4, 256, 0, stream>>>(X, eoff, xbf, flag);
        gemm_big<2,false><<<nb, 256, 0, stream>>>(xbf, nullptr, nullptr, Zr,
                WiT, bvec, Uf, Ub, nullptr, 0, flag, 0);
        gemm_big<1,false><<<nb, 256, 0, stream>>>(Ub, A1 + boff, V0b + boff, Zr,
                T0, Uf, Vf, Vb, nullptr, 0, flag, 1);
        gemm_big<0,false><<<nb, 256, 0, stream>>>(Vb, nullptr, nullptr, Zr,
                T1, Vf, Uf, Ub, nullptr, 0, flag, 2);
        gemm_big<0,false><<<nb, 256, 0, stream>>>(Ub, nullptr, nullptr, Zr,
                T2, Uf, Vf, Vb, nullptr, 0, flag, 4);
        gemm_big<0,true ><<<nb, 256, 0, stream>>>(Vb, nullptr, nullptr, Zr,
                T3, Vf, nullptr, nullptr, d_out, eoff, flag, 8);
    }
    gather_final<<<256, 256, 0, stream>>>(d_out, lens, flag);
}